// Round 16
// baseline (104.646 us; speedup 1.0000x reference)
//
#include <hip/hip_runtime.h>
#include <hip/hip_fp16.h>
#include <cstdint>
#include <cstddef>

// FastGRNN cell, MI355X fp16-MFMA, v16.
// stage1: PAGE-SEQUENTIAL A staging — each block stages its whole 32x512 f32
//         A-panel ONCE as contiguous full-row streams (f16 into persistent
//         32KB LDS, chunk-swizzled), then runs 8 k-iters with only B dbuf'd.
//         DRAM sees long sequential runs instead of 64-128B tile fragments.
//         3072 blocks x 256 thr, 64KB LDS -> 2 blocks/CU.
// reduce: rb6[8192][1536] -> rb2[8192][512] deterministic panel sums (proven).
// stage2: pre = rb2 @ [W2|U2]^T (K=512) + fused sigmoid/tanh epilogue (proven).

typedef _Float16 half8 __attribute__((ext_vector_type(8)));
typedef float f32x4 __attribute__((ext_vector_type(4)));

#define DIN 1024
#define DH 2048
#define RK 256
#define RB6LD 1536
// wb half-offsets
#define OFF_W1H 0
#define OFF_U1H 262144
#define OFF_W2H 786432
#define OFF_U2H 1310720

__device__ __forceinline__ half8 cvt8(const float4 a, const float4 b) {
  half8 h;
  h[0] = (_Float16)a.x; h[1] = (_Float16)a.y; h[2] = (_Float16)a.z; h[3] = (_Float16)a.w;
  h[4] = (_Float16)b.x; h[5] = (_Float16)b.y; h[6] = (_Float16)b.z; h[7] = (_Float16)b.w;
  return h;
}

// ---------------- prep: weights f32 -> f16 ----------------------------------
__global__ __launch_bounds__(256)
void fgrnn_prep(const float* __restrict__ W1, const float* __restrict__ U1,
                const float* __restrict__ W2, const float* __restrict__ U2,
                _Float16* __restrict__ wb) {
  const int q = blockIdx.x * 256 + threadIdx.x;
  const float* src;
  int rel;
  if (q < 65536) { src = W1; rel = q; }
  else if (q < 196608) { src = U1; rel = q - 65536; }
  else if (q < 327680) { src = W2; rel = q - 196608; }
  else { src = U2; rel = q - 327680; }
  const float4 v = reinterpret_cast<const float4*>(src)[rel];
  union { _Float16 h[4]; uint2 u; } cv;
  cv.h[0] = (_Float16)v.x; cv.h[1] = (_Float16)v.y;
  cv.h[2] = (_Float16)v.z; cv.h[3] = (_Float16)v.w;
  reinterpret_cast<uint2*>(wb)[q] = cv.u;
}

// ---------------- stage 1: persistent A-panel, page-sequential stage --------
// 3072 blocks x 256 thr. BM=32, BN=128, K-panel=512 (8 iters of BK=64).
// 4 waves 2x2; wave tile 16x64 (acc[4]). panel p<2: x kslice p; p>=2: h
// kslice p-2. ncol picks weight rows ncol*128..+128.
// A LDS [32][512] f16 persistent, 16B-chunk swizzle ch ^= (row&7) (<=2-way).
// B LDS [128][64] f16 dbuf, elem swizzle c ^= (r&7)<<3 (proven 0-conflict).
__global__ __launch_bounds__(256)
void fgrnn_stage1(const float* __restrict__ x, const float* __restrict__ h,
                  const _Float16* __restrict__ wb, _Float16* __restrict__ rb6) {
  __shared__ _Float16 Ap[32 * 512];      // 32 KB persistent
  __shared__ _Float16 Bs[2][128 * 64];   // 2 x 16 KB

  const int bid = blockIdx.x;
  const int L = (bid & 7) * 384 + (bid >> 3);   // XCD chunk swizzle (3072=8*384)
  const int p = L / 512;                        // 0..5 panel
  const int rem = L & 511;
  const int ncol = rem >> 8;                    // 0,1
  const int mtile = rem & 255;                  // 0..255
  const bool isx = (p < 2);
  const float* A = isx ? x : h;
  const int KA = isx ? DIN : DH;
  const int kbase = (isx ? p : (p - 2)) * 512;
  const _Float16* Bw = wb + (isx ? OFF_W1H : OFF_U1H) + (size_t)(ncol * 128) * KA;
  const int row0 = mtile * 32;
  const int colbase = p * 256 + ncol * 128;

  const int tid = threadIdx.x;
  const int lane = tid & 63;
  const int wv = tid >> 6;
  const int wr = wv >> 1, wc = wv & 1;

  // ---- A panel stage (once): 32 rows x 512 f32, sequential per-row runs ----
  // thread -> row tid>>3; 8 passes of 32B move left->right across the row.
  {
    const int ar = tid >> 3;            // 0..31
    const int ac0 = (tid & 7) * 8;      // f32 col base within 64-f32 stripe
    const float* src = A + (size_t)(row0 + ar) * KA + kbase;
#pragma unroll
    for (int pass = 0; pass < 8; ++pass) {
      const int c = ac0 + pass * 64;    // f32 col, ascending per pass
      const float4 v0 = *reinterpret_cast<const float4*>(src + c);
      const float4 v1 = *reinterpret_cast<const float4*>(src + c + 4);
      const int ch = (c >> 3) ^ (ar & 7);     // 16B-chunk swizzle
      *reinterpret_cast<half8*>(&Ap[ar * 512 + ch * 8]) = cvt8(v0, v1);
    }
  }

  // ---- B staging (R10-proven pattern) ----
  const int sr = tid >> 3;        // 0..31
  const int sc = (tid & 7) * 8;
  half8 pb[4];
  auto LOADB = [&](int it) {
    const int k0 = kbase + it * 64;
#pragma unroll
    for (int j = 0; j < 4; ++j)
      pb[j] = *reinterpret_cast<const half8*>(Bw + (size_t)(j * 32 + sr) * KA + k0 + sc);
  };
  auto STOREB = [&](int buf) {
#pragma unroll
    for (int j = 0; j < 4; ++j) {
      const int r = j * 32 + sr;
      *reinterpret_cast<half8*>(&Bs[buf][r * 64 + (sc ^ ((r & 7) << 3))]) = pb[j];
    }
  };

  f32x4 acc[4];
#pragma unroll
  for (int j = 0; j < 4; ++j) acc[j] = (f32x4){0.f, 0.f, 0.f, 0.f};

  LOADB(0);
  STOREB(0);
  __syncthreads();    // A-panel + B0 both resident

  for (int it = 0; it < 8; ++it) {
    const bool more = (it + 1 < 8);
    const int buf = it & 1;
    if (more) LOADB(it + 1);
#pragma unroll
    for (int kk = 0; kk < 64; kk += 32) {
      const int r = wr * 16 + (lane & 15);
      const int chA = (it * 8 + (kk >> 3) + (lane >> 4)) ^ (r & 7);
      const half8 af = *reinterpret_cast<const half8*>(&Ap[r * 512 + chA * 8]);
      half8 bf[4];
#pragma unroll
      for (int ni = 0; ni < 4; ++ni) {
        const int rb_ = wc * 64 + ni * 16 + (lane & 15);
        bf[ni] = *reinterpret_cast<const half8*>(
            &Bs[buf][rb_ * 64 + ((kk + 8 * (lane >> 4)) ^ ((rb_ & 7) << 3))]);
      }
#pragma unroll
      for (int ni = 0; ni < 4; ++ni)
        acc[ni] = __builtin_amdgcn_mfma_f32_16x16x32_f16(af, bf[ni], acc[ni], 0, 0, 0);
    }
    if (more) {
      __syncthreads();
      STOREB(buf ^ 1);
    }
    __syncthreads();
  }

  // D layout (16x16 family): row = 4*(lane>>4)+e, col = lane&15.
#pragma unroll
  for (int ni = 0; ni < 4; ++ni)
#pragma unroll
    for (int e = 0; e < 4; ++e) {
      const int row = row0 + wr * 16 + 4 * (lane >> 4) + e;
      const int col = colbase + wc * 64 + ni * 16 + (lane & 15);
      rb6[(size_t)row * RB6LD + col] = (_Float16)acc[ni][e];
    }
}

// ---------------- reduce: rb6[8192][1536] -> rb2[8192][512] -----------------
__global__ __launch_bounds__(256)
void fgrnn_reduce(const _Float16* __restrict__ rb6, _Float16* __restrict__ rb2) {
  const int t = blockIdx.x * 256 + threadIdx.x;  // 0..524287
  const int row = t >> 6;
  const int ch = t & 63;
  const _Float16* src = rb6 + (size_t)row * RB6LD;
  half8 s;
  int outcol;
  if (ch < 32) {  // wx = p0 + p1
    const int c = ch * 8;
    s = *reinterpret_cast<const half8*>(src + c) +
        *reinterpret_cast<const half8*>(src + 256 + c);
    outcol = c;
  } else {        // uh = p2 + p3 + p4 + p5
    const int c = (ch - 32) * 8;
    const _Float16* su = src + 512;
    s = *reinterpret_cast<const half8*>(su + c) +
        *reinterpret_cast<const half8*>(su + 256 + c);
    s = s + *reinterpret_cast<const half8*>(su + 512 + c);
    s = s + *reinterpret_cast<const half8*>(su + 768 + c);
    outcol = 256 + c;
  }
  *reinterpret_cast<half8*>(rb2 + (size_t)row * 512 + outcol) = s;
}

// ---------------- stage 2: pre = rb2 @ [W2|U2]^T, K=512 (proven) ------------
__global__ __launch_bounds__(256)
void fgrnn_stage2(const _Float16* __restrict__ rb2, const _Float16* __restrict__ wb,
                  const float* __restrict__ state,
                  const float* __restrict__ bg, const float* __restrict__ bu,
                  const float* __restrict__ zeta, const float* __restrict__ nu,
                  float* __restrict__ out) {
  const int bid = blockIdx.x;
  const int L = (bid & 7) * 256 + (bid >> 3);   // XCD swizzle: mtile-banded
  const int mtile = L >> 4;   // 0..127
  const int ntile = L & 15;   // 0..15
  const int row0 = mtile * 64;
  const int col0 = ntile * 128;
  const _Float16* W2h = wb + OFF_W2H;
  const _Float16* U2h = wb + OFF_U2H;

  __shared__ _Float16 As[64 * 64];
  __shared__ _Float16 Bs[128 * 64];

  const int tid = threadIdx.x;
  const int lane = tid & 63;
  const int w = tid >> 6;
  const int wr = w >> 1, wc = w & 1;

  f32x4 acc[2][4];
#pragma unroll
  for (int i = 0; i < 2; ++i)
#pragma unroll
    for (int j = 0; j < 4; ++j) acc[i][j] = (f32x4){0.f, 0.f, 0.f, 0.f};

  const int sr = tid >> 3;      // 0..31
  const int sc = (tid & 7) * 8;

  half8 pa[2], pb[4];

  auto LOADG = [&](int it) {
    const int k0 = it * 64;
#pragma unroll
    for (int j = 0; j < 2; ++j)
      pa[j] = *reinterpret_cast<const half8*>(rb2 + (size_t)(row0 + j * 32 + sr) * 512 + k0 + sc);
    const _Float16* Bh = (k0 < 256) ? W2h : U2h;
    const int kb = k0 & 255;
#pragma unroll
    for (int j = 0; j < 4; ++j)
      pb[j] = *reinterpret_cast<const half8*>(Bh + (size_t)(col0 + j * 32 + sr) * RK + kb + sc);
  };
  auto STORE = [&]() {
#pragma unroll
    for (int j = 0; j < 2; ++j) {
      const int r = j * 32 + sr;
      *reinterpret_cast<half8*>(&As[r * 64 + (sc ^ ((r & 7) << 3))]) = pa[j];
    }
#pragma unroll
    for (int j = 0; j < 4; ++j) {
      const int r = j * 32 + sr;
      *reinterpret_cast<half8*>(&Bs[r * 64 + (sc ^ ((r & 7) << 3))]) = pb[j];
    }
  };

  LOADG(0);
  STORE();
  __syncthreads();

  for (int it = 0; it < 8; ++it) {
    const bool more = (it + 1 < 8);
    if (more) LOADG(it + 1);
#pragma unroll
    for (int kk = 0; kk < 64; kk += 32) {
      half8 af[2], bf[4];
#pragma unroll
      for (int mi = 0; mi < 2; ++mi) {
        const int r = wr * 32 + mi * 16 + (lane & 15);
        af[mi] = *reinterpret_cast<const half8*>(
            &As[r * 64 + ((kk + 8 * (lane >> 4)) ^ ((r & 7) << 3))]);
      }
#pragma unroll
      for (int ni = 0; ni < 4; ++ni) {
        const int r = wc * 64 + ni * 16 + (lane & 15);
        bf[ni] = *reinterpret_cast<const half8*>(
            &Bs[r * 64 + ((kk + 8 * (lane >> 4)) ^ ((r & 7) << 3))]);
      }
#pragma unroll
      for (int mi = 0; mi < 2; ++mi)
#pragma unroll
        for (int ni = 0; ni < 4; ++ni)
          acc[mi][ni] =
              __builtin_amdgcn_mfma_f32_16x16x32_f16(af[mi], bf[ni], acc[mi][ni], 0, 0, 0);
    }
    if (more) {
      __syncthreads();
      STORE();
    }
    __syncthreads();
  }

  // Fused epilogue (fast exp2/rcp; asymptotes correct)
  const float LOG2E = 1.44269504f;
  const float sz = __builtin_amdgcn_rcpf(1.f + __builtin_amdgcn_exp2f(-zeta[0] * LOG2E));
  const float sn = __builtin_amdgcn_rcpf(1.f + __builtin_amdgcn_exp2f(-nu[0] * LOG2E));
#pragma unroll
  for (int mi = 0; mi < 2; ++mi)
#pragma unroll
    for (int ni = 0; ni < 4; ++ni) {
      const int col = col0 + wc * 64 + ni * 16 + (lane & 15);
      const float bgc = bg[col];
      const float buc = bu[col];
#pragma unroll
      for (int e = 0; e < 4; ++e) {
        const int row = row0 + wr * 32 + mi * 16 + 4 * (lane >> 4) + e;
        const float pre = acc[mi][ni][e];
        const float zg =
            __builtin_amdgcn_rcpf(1.f + __builtin_amdgcn_exp2f(-(pre + bgc) * LOG2E));
        const float hc =
            1.f - 2.f * __builtin_amdgcn_rcpf(
                            1.f + __builtin_amdgcn_exp2f((pre + buc) * (2.f * LOG2E)));
        const float sv = state[(size_t)row * DH + col];
        out[(size_t)row * DH + col] = zg * sv + (sz * (1.f - zg) + sn) * hc;
      }
    }
}

extern "C" void kernel_launch(void* const* d_in, const int* in_sizes, int n_in,
                              void* d_out, int out_size, void* d_ws, size_t ws_size,
                              hipStream_t stream) {
  const float* input = (const float*)d_in[0];
  const float* state = (const float*)d_in[1];
  const float* W1 = (const float*)d_in[2];
  const float* W2 = (const float*)d_in[3];
  const float* U1 = (const float*)d_in[4];
  const float* U2 = (const float*)d_in[5];
  const float* bg = (const float*)d_in[6];
  const float* bu = (const float*)d_in[7];
  const float* zeta = (const float*)d_in[8];
  const float* nu = (const float*)d_in[9];
  float* out = (float*)d_out;

  _Float16* rb6 = (_Float16*)d_ws;                      // 8192*1536*2 = 25.2 MB
  _Float16* rb2 = rb6 + (size_t)8192 * RB6LD;           // 8.4 MB
  _Float16* wb = rb2 + (size_t)8192 * 512;              // 3.67 MB (37.3 MB total)

  fgrnn_prep<<<1792, 256, 0, stream>>>(W1, U1, W2, U2, wb);
  fgrnn_stage1<<<3072, 256, 0, stream>>>(input, state, wb, rb6);
  fgrnn_reduce<<<2048, 256, 0, stream>>>(rb6, rb2);
  fgrnn_stage2<<<2048, 256, 0, stream>>>(rb2, wb, state, bg, bu, zeta, nu, out);
}